// Round 8
// baseline (108.862 us; speedup 1.0000x reference)
//
#include <hip/hip_runtime.h>
#include <hip/hip_bf16.h>

#define C_DIM 128
#define H_DIM 32

typedef __attribute__((ext_vector_type(8))) short bf16x8;
typedef __attribute__((ext_vector_type(4))) float f32x4;

// fast tanh: tanh(x) = 1 - 2/(e^{2x}+1). Handles +-inf correctly.
__device__ __forceinline__ float tanh_fast(float x) {
    float e = __expf(2.0f * x);
    return 1.0f - 2.0f * __builtin_amdgcn_rcpf(e + 1.0f);
}

// f32 -> bf16 RNE via library cast (compiler emits v_cvt_pk_bf16_f32 pairs)
__device__ __forceinline__ short f2bf(float f) {
    return __builtin_bit_cast(short, __float2bfloat16(f));
}

// Chebyshev -> monomial: p(t) = e0 + e1 t + e2 t^2 + e3 t^3 + e4 t^4
//   e0 = c0 - c2 + c4; e1 = c1 - 3c3; e2 = 2c2 - 8c4; e3 = 4c3; e4 = 8c4
// e0 folded into bias1 (summed over channels).
// Layer-1 coeffs packed directly in MFMA B-fragment order (bf16); the
// A-builder uses the IDENTICAL (lane,j)->(channel,power) map, so any hw
// k-permutation cancels (A/B fragment layouts are symmetric).
__global__ void prep_kernel(const float* __restrict__ c1, const float* __restrict__ c2,
                            unsigned short* __restrict__ Bpack, float* __restrict__ bias1,
                            float* __restrict__ E2, float* __restrict__ bias2) {
    const int tid = threadIdx.x;
    const int idx = blockIdx.x * 256 + tid;   // grid 64*256 = 16384 = one per element
    {
        int kc = idx >> 10;
        int oh = (idx >> 9) & 1;
        int l  = (idx >> 3) & 63;
        int j  = idx & 7;
        int g  = l >> 4;
        int kc2 = kc >> 1, kh = kc & 1;
        int c   = kc2 * 16 + 4 * g + 2 * kh + (j >> 2);
        int col = oh * 16 + (l & 15);
        int p   = j & 3;
        const float* cc = c1 + (c * H_DIM + col) * 5;
        float v = (p == 0) ? cc[1] - 3.0f * cc[3]
                : (p == 1) ? 2.0f * cc[2] - 8.0f * cc[4]
                : (p == 2) ? 4.0f * cc[3]
                           : 8.0f * cc[4];
        Bpack[idx] = (unsigned short)f2bf(v);
    }
    if (blockIdx.x == 0) {
        __shared__ float part[256];
        const int o = tid & 31, ch = tid >> 5;
        float b = 0.0f;
        for (int i = ch * 16; i < ch * 16 + 16; ++i) {
            const float* cc = c1 + (i * H_DIM + o) * 5;
            b += cc[0] - cc[2] + cc[4];
        }
        part[tid] = b;
        __syncthreads();
        if (tid < 32) {
            float s = 0.0f;
            #pragma unroll
            for (int k = 0; k < 8; ++k) s += part[k * 32 + tid];
            bias1[tid] = s;
            const float* cc = c2 + tid * 5;
            float4 e;
            e.x = cc[1] - 3.0f * cc[3];
            e.y = 2.0f * cc[2] - 8.0f * cc[4];
            e.z = 4.0f * cc[3];
            e.w = 8.0f * cc[4];
            reinterpret_cast<float4*>(E2)[tid] = e;
        }
        __syncthreads();
        if (tid < 32) part[tid] = c2[tid * 5] - c2[tid * 5 + 2] + c2[tid * 5 + 4];
        __syncthreads();
        if (tid == 0) {
            float b2 = 0.0f;
            for (int h = 0; h < 32; ++h) b2 += part[h];
            bias2[0] = b2;
        }
    }
}

// Kernel A: ChebyKAN GEMM -> LN -> ReLU -> ChebyKAN2 -> sigmoid -> scale[N].
// Homogeneous read-stream (PR 134 MB) + tiny write (1 MB). R6's best GEMM
// structure, epilogue writes per-row scale instead of sweeping PRV.
__global__ __launch_bounds__(512, 4) void scale_kernel(
        const float* __restrict__ PR,
        const unsigned short* __restrict__ Bpack, const float* __restrict__ bias1,
        const float* __restrict__ E2, const float* __restrict__ bias2,
        const float* __restrict__ gamma, const float* __restrict__ beta,
        const float* __restrict__ alphap, float* __restrict__ scale_out) {
    __shared__ short sB[16 * 2 * 64 * 8];   // 32 KB: B-frags in lane order
    __shared__ float s_scale[256];

    const int tid  = threadIdx.x;
    const int wid  = tid >> 6;
    const int lane = tid & 63;
    const int g    = lane >> 4;
    const int lr   = lane & 15;

    const float4* pr4 = reinterpret_cast<const float4*>(PR);
    const size_t rbase = (size_t)blockIdx.x * 256 + wid * 32 + lr;
    const float4* q0 = pr4 + (rbase +  0) * (C_DIM / 4) + g;
    const float4* q1 = pr4 + (rbase + 16) * (C_DIM / 4) + g;

    // stage B fragments into LDS, coalesced (32 KB / 512 thr = 4 float4 each)
    {
        const float4* src = reinterpret_cast<const float4*>(Bpack);
        float4* dst = reinterpret_cast<float4*>(sB);
        #pragma unroll
        for (int j = 0; j < 4; ++j) dst[j * 512 + tid] = src[j * 512 + tid];
    }
    __syncthreads();

    const float gam0 = gamma[lr], gam1 = gamma[16 + lr];
    const float bet0 = beta[lr],  bet1 = beta[16 + lr];
    const float4 e2a = reinterpret_cast<const float4*>(E2)[lr];
    const float4 e2b = reinterpret_cast<const float4*>(E2)[16 + lr];
    const float zb = bias2[0];
    const float alpha = alphap[0];

    f32x4 acc[2][2];
    {
        float b0 = bias1[lr], b1 = bias1[16 + lr];
        #pragma unroll
        for (int t = 0; t < 2; ++t) {
            acc[t][0] = (f32x4){b0, b0, b0, b0};
            acc[t][1] = (f32x4){b1, b1, b1, b1};
        }
    }

    const bf16x8* sB8 = reinterpret_cast<const bf16x8*>(sB);

    #pragma unroll
    for (int kc2 = 0; kc2 < 8; ++kc2) {
        float4 x0 = q0[kc2 * 4];
        float4 x1 = q1[kc2 * 4];
        bf16x8 be0 = sB8[(kc2 * 4 + 0) * 64 + lane];
        bf16x8 be1 = sB8[(kc2 * 4 + 1) * 64 + lane];
        bf16x8 bo0 = sB8[(kc2 * 4 + 2) * 64 + lane];
        bf16x8 bo1 = sB8[(kc2 * 4 + 3) * 64 + lane];
        #define DO_TILE(XC, T) { \
            float t0 = tanh_fast(XC.x), t1 = tanh_fast(XC.y); \
            float t2 = tanh_fast(XC.z), t3 = tanh_fast(XC.w); \
            float s0 = t0 * t0, s1 = t1 * t1, s2 = t2 * t2, s3 = t3 * t3; \
            bf16x8 ae, ao; \
            ae[0] = f2bf(t0); ae[1] = f2bf(s0); ae[2] = f2bf(s0 * t0); ae[3] = f2bf(s0 * s0); \
            ae[4] = f2bf(t1); ae[5] = f2bf(s1); ae[6] = f2bf(s1 * t1); ae[7] = f2bf(s1 * s1); \
            ao[0] = f2bf(t2); ao[1] = f2bf(s2); ao[2] = f2bf(s2 * t2); ao[3] = f2bf(s2 * s2); \
            ao[4] = f2bf(t3); ao[5] = f2bf(s3); ao[6] = f2bf(s3 * t3); ao[7] = f2bf(s3 * s3); \
            acc[T][0] = __builtin_amdgcn_mfma_f32_16x16x32_bf16(ae, be0, acc[T][0], 0, 0, 0); \
            acc[T][1] = __builtin_amdgcn_mfma_f32_16x16x32_bf16(ae, be1, acc[T][1], 0, 0, 0); \
            acc[T][0] = __builtin_amdgcn_mfma_f32_16x16x32_bf16(ao, bo0, acc[T][0], 0, 0, 0); \
            acc[T][1] = __builtin_amdgcn_mfma_f32_16x16x32_bf16(ao, bo1, acc[T][1], 0, 0, 0); }
        DO_TILE(x0, 0)
        DO_TILE(x1, 1)
        #undef DO_TILE
    }

    // ---- LayerNorm + ReLU + layer-2 ChebyKAN + sigmoid, per M-tile ----
    // C layout: col = oh*16 + lr, row = g*4 + reg  (verified m89/m91)
    #pragma unroll
    for (int t = 0; t < 2; ++t) {
        f32x4 a0 = acc[t][0], a1 = acc[t][1];
        float s[4], vs[4], z[4];
        #pragma unroll
        for (int r = 0; r < 4; ++r) s[r] = a0[r] + a1[r];
        #pragma unroll
        for (int m = 1; m <= 8; m <<= 1) {
            #pragma unroll
            for (int r = 0; r < 4; ++r) s[r] += __shfl_xor(s[r], m, 64);
        }
        #pragma unroll
        for (int r = 0; r < 4; ++r) {
            float mu = s[r] * (1.0f / 32.0f);
            float d0 = a0[r] - mu, d1 = a1[r] - mu;
            a0[r] = d0; a1[r] = d1;
            vs[r] = d0 * d0 + d1 * d1;
        }
        #pragma unroll
        for (int m = 1; m <= 8; m <<= 1) {
            #pragma unroll
            for (int r = 0; r < 4; ++r) vs[r] += __shfl_xor(vs[r], m, 64);
        }
        #pragma unroll
        for (int r = 0; r < 4; ++r) {
            float rs = rsqrtf(vs[r] * (1.0f / 32.0f) + 1e-5f);
            float h0 = fmaf(a0[r] * rs, gam0, bet0);
            float h1 = fmaf(a1[r] * rs, gam1, bet1);
            h0 = fmaxf(h0, 0.0f); h1 = fmaxf(h1, 0.0f);
            float t0 = tanh_fast(h0), t1 = tanh_fast(h1);
            float t02 = t0 * t0, t12 = t1 * t1;
            float zp = fmaf(e2a.x, t0, fmaf(e2a.y, t02,
                        fmaf(e2a.z, t02 * t0, e2a.w * (t02 * t02))));
            zp += fmaf(e2b.x, t1, fmaf(e2b.y, t12,
                    fmaf(e2b.z, t12 * t1, e2b.w * (t12 * t12))));
            z[r] = zp;
        }
        #pragma unroll
        for (int m = 1; m <= 8; m <<= 1) {
            #pragma unroll
            for (int r = 0; r < 4; ++r) z[r] += __shfl_xor(z[r], m, 64);
        }
        if (lr == 0) {
            #pragma unroll
            for (int r = 0; r < 4; ++r) {
                float attn = __builtin_amdgcn_rcpf(1.0f + __expf(-(z[r] + zb)));
                s_scale[wid * 32 + t * 16 + g * 4 + r] = fmaf(alpha, attn, 1.0f);
            }
        }
    }
    __syncthreads();

    // coalesced scale write: 256 rows per block
    if (tid < 256) scale_out[blockIdx.x * 256 + tid] = s_scale[tid];
}

// Kernel B: pure streaming gate, m13 float4-copy pattern + broadcast scale.
// 2048 blocks x 256 thr, 16 float4/thread grid-stride.
__global__ __launch_bounds__(256) void gate_kernel(
        const float* __restrict__ PRV, const float* __restrict__ scale,
        float* __restrict__ out) {
    const int tid = blockIdx.x * 256 + threadIdx.x;
    const f32x4* in4 = reinterpret_cast<const f32x4*>(PRV);
    f32x4* out4 = reinterpret_cast<f32x4*>(out);
    #pragma unroll
    for (int it = 0; it < 16; ++it) {
        int i = tid + it * (2048 * 256);
        float sc = scale[i >> 5];      // 32 float4 per row; L2-hot (1 MB)
        f32x4 v = in4[i];
        v[0] *= sc; v[1] *= sc; v[2] *= sc; v[3] *= sc;
        out4[i] = v;
    }
}

extern "C" void kernel_launch(void* const* d_in, const int* in_sizes, int n_in,
                              void* d_out, int out_size, void* d_ws, size_t ws_size,
                              hipStream_t stream) {
    const float* PRV    = (const float*)d_in[0];
    const float* PR     = (const float*)d_in[1];
    const float* c1     = (const float*)d_in[2];
    const float* gamma  = (const float*)d_in[3];
    const float* beta   = (const float*)d_in[4];
    const float* c2     = (const float*)d_in[5];
    const float* alphap = (const float*)d_in[6];
    float* out = (float*)d_out;

    unsigned short* Bpack = (unsigned short*)d_ws;            // 32 KB bf16 frags
    float* wsf   = (float*)((char*)d_ws + 32768);
    float* bias1 = wsf;          // 32
    float* E2    = wsf + 32;     // 128 (32 x float4)
    float* bias2 = wsf + 160;    // 1
    float* scale = wsf + 192;    // N floats (1 MB)

    const int N = in_sizes[0] / C_DIM;

    hipLaunchKernelGGL(prep_kernel, dim3(64), dim3(256), 0, stream,
                       c1, c2, Bpack, bias1, E2, bias2);
    hipLaunchKernelGGL(scale_kernel, dim3(N / 256), dim3(512), 0, stream,
                       PR, Bpack, bias1, E2, bias2, gamma, beta, alphap, scale);
    hipLaunchKernelGGL(gate_kernel, dim3(2048), dim3(256), 0, stream,
                       PRV, scale, out);
}

// Round 10
// 87.359 us; speedup vs baseline: 1.2461x; 1.2461x over previous
//
#include <hip/hip_runtime.h>
#include <hip/hip_bf16.h>

#define C_DIM 128
#define H_DIM 32

typedef __attribute__((ext_vector_type(8))) short bf16x8;
typedef __attribute__((ext_vector_type(4))) float f32x4;

// fast tanh: tanh(x) = 1 - 2/(e^{2x}+1). Handles +-inf correctly.
__device__ __forceinline__ float tanh_fast(float x) {
    float e = __expf(2.0f * x);
    return 1.0f - 2.0f * __builtin_amdgcn_rcpf(e + 1.0f);
}

// f32 -> bf16 RNE via library cast (compiler emits v_cvt_pk_bf16_f32 pairs)
__device__ __forceinline__ short f2bf(float f) {
    return __builtin_bit_cast(short, __float2bfloat16(f));
}

// Chebyshev -> monomial: p(t) = e0 + e1 t + e2 t^2 + e3 t^3 + e4 t^4
//   e0 = c0 - c2 + c4; e1 = c1 - 3c3; e2 = 2c2 - 8c4; e3 = 4c3; e4 = 8c4
// e0 folded into bias1 (summed over channels).
// Layer-1 coeffs packed directly in MFMA B-fragment order (bf16); the
// A-builder uses the IDENTICAL (lane,j)->(channel,power) map, so any hw
// k-permutation cancels (A/B fragment layouts are symmetric).
__global__ void prep_kernel(const float* __restrict__ c1, const float* __restrict__ c2,
                            unsigned short* __restrict__ Bpack, float* __restrict__ bias1,
                            float* __restrict__ E2, float* __restrict__ bias2) {
    const int tid = threadIdx.x;
    const int idx = blockIdx.x * 256 + tid;   // grid 64*256 = 16384 = one per element
    {
        int kc = idx >> 10;
        int oh = (idx >> 9) & 1;
        int l  = (idx >> 3) & 63;
        int j  = idx & 7;
        int g  = l >> 4;
        int kc2 = kc >> 1, kh = kc & 1;
        int c   = kc2 * 16 + 4 * g + 2 * kh + (j >> 2);
        int col = oh * 16 + (l & 15);
        int p   = j & 3;
        const float* cc = c1 + (c * H_DIM + col) * 5;
        float v = (p == 0) ? cc[1] - 3.0f * cc[3]
                : (p == 1) ? 2.0f * cc[2] - 8.0f * cc[4]
                : (p == 2) ? 4.0f * cc[3]
                           : 8.0f * cc[4];
        Bpack[idx] = (unsigned short)f2bf(v);
    }
    if (blockIdx.x == 0) {
        __shared__ float part[256];
        const int o = tid & 31, ch = tid >> 5;
        float b = 0.0f;
        for (int i = ch * 16; i < ch * 16 + 16; ++i) {
            const float* cc = c1 + (i * H_DIM + o) * 5;
            b += cc[0] - cc[2] + cc[4];
        }
        part[tid] = b;
        __syncthreads();
        if (tid < 32) {
            float s = 0.0f;
            #pragma unroll
            for (int k = 0; k < 8; ++k) s += part[k * 32 + tid];
            bias1[tid] = s;
            const float* cc = c2 + tid * 5;
            float4 e;
            e.x = cc[1] - 3.0f * cc[3];
            e.y = 2.0f * cc[2] - 8.0f * cc[4];
            e.z = 4.0f * cc[3];
            e.w = 8.0f * cc[4];
            reinterpret_cast<float4*>(E2)[tid] = e;
        }
        __syncthreads();
        if (tid < 32) part[tid] = c2[tid * 5] - c2[tid * 5 + 2] + c2[tid * 5 + 4];
        __syncthreads();
        if (tid == 0) {
            float b2 = 0.0f;
            for (int h = 0; h < 32; ++h) b2 += part[h];
            bias2[0] = b2;
        }
    }
}

// R9b: fused; GEMM-phase PR loads are an asm-pinned depth-8 pipeline:
// issue 8 global_load_dwordx4, then per K-step {s_waitcnt vmcnt(N)
// value-tied to the consumed regs; issue next 2; compute}. No stores exist
// between issue and consume, so decreasing vmcnt counts are exact; any
// compiler-inserted vmem op only makes waits conservative (safe).
__global__ __launch_bounds__(512, 4) void fused_kernel(
        const float* __restrict__ PRV, const float* __restrict__ PR,
        const unsigned short* __restrict__ Bpack, const float* __restrict__ bias1,
        const float* __restrict__ E2, const float* __restrict__ bias2,
        const float* __restrict__ gamma, const float* __restrict__ beta,
        const float* __restrict__ alphap, float* __restrict__ out) {
    __shared__ short sB[16 * 2 * 64 * 8];   // 32 KB: B-frags in lane order
    __shared__ float s_scale[256];

    const int tid  = threadIdx.x;
    const int wid  = tid >> 6;
    const int lane = tid & 63;
    const int g    = lane >> 4;
    const int lr   = lane & 15;

    const float4* pr4 = reinterpret_cast<const float4*>(PR);
    const size_t rbase = (size_t)blockIdx.x * 256 + wid * 32 + lr;
    const float4* q0 = pr4 + (rbase +  0) * (C_DIM / 4) + g;
    const float4* q1 = pr4 + (rbase + 16) * (C_DIM / 4) + g;

    // epilogue constants FIRST (their vector loads must never enter the
    // pinned-load queue window); e2a/e2b as ext-vectors (legal "v" operands)
    const float gam0 = gamma[lr], gam1 = gamma[16 + lr];
    const float bet0 = beta[lr],  bet1 = beta[16 + lr];
    const f32x4 e2a = reinterpret_cast<const f32x4*>(E2)[lr];
    const f32x4 e2b = reinterpret_cast<const f32x4*>(E2)[16 + lr];
    const float zb = bias2[0];
    const float alpha = alphap[0];
    const float b0i = bias1[lr], b1i = bias1[16 + lr];

    // stage B fragments into LDS, coalesced (32 KB / 512 thr = 4 float4 each)
    {
        const float4* src = reinterpret_cast<const float4*>(Bpack);
        float4* dst = reinterpret_cast<float4*>(sB);
        #pragma unroll
        for (int j = 0; j < 4; ++j) dst[j * 512 + tid] = src[j * 512 + tid];
    }
    __syncthreads();   // drains vmcnt to 0 (compiler emits waitcnt before barrier)

    // pin all epilogue constants live here (scalar components only):
    // forces their loads complete before the pinned PR-load block below
    asm volatile("" :: "v"(gam0), "v"(gam1), "v"(bet0), "v"(bet1),
                       "v"(e2a[0]), "v"(e2a[1]), "v"(e2a[2]), "v"(e2a[3]),
                       "v"(e2b[0]), "v"(e2b[1]), "v"(e2b[2]), "v"(e2b[3]),
                       "v"(zb), "v"(alpha), "v"(b0i), "v"(b1i));
    __builtin_amdgcn_sched_barrier(0);

    f32x4 pa0, pa1, pa2, pa3, pa4, pa5, pa6, pa7;
    f32x4 pb0, pb1, pb2, pb3, pb4, pb5, pb6, pb7;
    // issue kc2 in order (a then b): queue position of pa#K = 2K, pb#K = 2K+1
    #define ISSUE(K, BOFF) \
        asm volatile("global_load_dwordx4 %0, %1, off offset:" #BOFF \
                     : "=v"(pa##K) : "v"(q0)); \
        asm volatile("global_load_dwordx4 %0, %1, off offset:" #BOFF \
                     : "=v"(pb##K) : "v"(q1));
    ISSUE(0, 0) ISSUE(1, 64) ISSUE(2, 128) ISSUE(3, 192)

    f32x4 acc[2][2];
    #pragma unroll
    for (int t = 0; t < 2; ++t) {
        acc[t][0] = (f32x4){b0i, b0i, b0i, b0i};
        acc[t][1] = (f32x4){b1i, b1i, b1i, b1i};
    }

    const bf16x8* sB8 = reinterpret_cast<const bf16x8*>(sB);

    #define DO_TILE(XC, T) { \
        float t0 = tanh_fast(XC[0]), t1 = tanh_fast(XC[1]); \
        float t2 = tanh_fast(XC[2]), t3 = tanh_fast(XC[3]); \
        float s0 = t0 * t0, s1 = t1 * t1, s2 = t2 * t2, s3 = t3 * t3; \
        bf16x8 ae, ao; \
        ae[0] = f2bf(t0); ae[1] = f2bf(s0); ae[2] = f2bf(s0 * t0); ae[3] = f2bf(s0 * s0); \
        ae[4] = f2bf(t1); ae[5] = f2bf(s1); ae[6] = f2bf(s1 * t1); ae[7] = f2bf(s1 * s1); \
        ao[0] = f2bf(t2); ao[1] = f2bf(s2); ao[2] = f2bf(s2 * t2); ao[3] = f2bf(s2 * s2); \
        ao[4] = f2bf(t3); ao[5] = f2bf(s3); ao[6] = f2bf(s3 * t3); ao[7] = f2bf(s3 * s3); \
        acc[T][0] = __builtin_amdgcn_mfma_f32_16x16x32_bf16(ae, be0, acc[T][0], 0, 0, 0); \
        acc[T][1] = __builtin_amdgcn_mfma_f32_16x16x32_bf16(ae, be1, acc[T][1], 0, 0, 0); \
        acc[T][0] = __builtin_amdgcn_mfma_f32_16x16x32_bf16(ao, bo0, acc[T][0], 0, 0, 0); \
        acc[T][1] = __builtin_amdgcn_mfma_f32_16x16x32_bf16(ao, bo1, acc[T][1], 0, 0, 0); }

    // WAIT: consume pa#K/pb#K (queue slots 2K,2K+1 of this block's pinned
    // loads). N chosen so >= (2K+2) oldest ops have retired even with the
    // +2 reissues per prior step. Extra compiler vmem ops only over-wait.
    #define WAITK(K, N) \
        asm volatile("s_waitcnt vmcnt(" #N ")" : "+v"(pa##K), "+v"(pb##K));
    #define STEP(K) { \
        bf16x8 be0 = sB8[(K * 4 + 0) * 64 + lane]; \
        bf16x8 be1 = sB8[(K * 4 + 1) * 64 + lane]; \
        bf16x8 bo0 = sB8[(K * 4 + 2) * 64 + lane]; \
        bf16x8 bo1 = sB8[(K * 4 + 3) * 64 + lane]; \
        DO_TILE(pa##K, 0) \
        DO_TILE(pb##K, 1) }

    WAITK(0, 6) ISSUE(4, 256) STEP(0)
    WAITK(1, 6) ISSUE(5, 320) STEP(1)
    WAITK(2, 6) ISSUE(6, 384) STEP(2)
    WAITK(3, 6) ISSUE(7, 448) STEP(3)
    WAITK(4, 6) STEP(4)
    WAITK(5, 4) STEP(5)
    WAITK(6, 2) STEP(6)
    WAITK(7, 0) STEP(7)
    #undef WAITK
    #undef STEP
    #undef ISSUE
    #undef DO_TILE

    // ---- LayerNorm + ReLU + layer-2 ChebyKAN + sigmoid, per M-tile ----
    // C layout: col = oh*16 + lr, row = g*4 + reg  (verified m89/m91)
    #pragma unroll
    for (int t = 0; t < 2; ++t) {
        f32x4 a0 = acc[t][0], a1 = acc[t][1];
        float s[4], vs[4], z[4];
        #pragma unroll
        for (int r = 0; r < 4; ++r) s[r] = a0[r] + a1[r];
        #pragma unroll
        for (int m = 1; m <= 8; m <<= 1) {
            #pragma unroll
            for (int r = 0; r < 4; ++r) s[r] += __shfl_xor(s[r], m, 64);
        }
        #pragma unroll
        for (int r = 0; r < 4; ++r) {
            float mu = s[r] * (1.0f / 32.0f);
            float d0 = a0[r] - mu, d1 = a1[r] - mu;
            a0[r] = d0; a1[r] = d1;
            vs[r] = d0 * d0 + d1 * d1;
        }
        #pragma unroll
        for (int m = 1; m <= 8; m <<= 1) {
            #pragma unroll
            for (int r = 0; r < 4; ++r) vs[r] += __shfl_xor(vs[r], m, 64);
        }
        #pragma unroll
        for (int r = 0; r < 4; ++r) {
            float rs = rsqrtf(vs[r] * (1.0f / 32.0f) + 1e-5f);
            float h0 = fmaf(a0[r] * rs, gam0, bet0);
            float h1 = fmaf(a1[r] * rs, gam1, bet1);
            h0 = fmaxf(h0, 0.0f); h1 = fmaxf(h1, 0.0f);
            float t0 = tanh_fast(h0), t1 = tanh_fast(h1);
            float t02 = t0 * t0, t12 = t1 * t1;
            float zp = fmaf(e2a[0], t0, fmaf(e2a[1], t02,
                        fmaf(e2a[2], t02 * t0, e2a[3] * (t02 * t02))));
            zp += fmaf(e2b[0], t1, fmaf(e2b[1], t12,
                    fmaf(e2b[2], t12 * t1, e2b[3] * (t12 * t12))));
            z[r] = zp;
        }
        #pragma unroll
        for (int m = 1; m <= 8; m <<= 1) {
            #pragma unroll
            for (int r = 0; r < 4; ++r) z[r] += __shfl_xor(z[r], m, 64);
        }
        if (lr == 0) {
            #pragma unroll
            for (int r = 0; r < 4; ++r) {
                float attn = __builtin_amdgcn_rcpf(1.0f + __expf(-(z[r] + zb)));
                s_scale[wid * 32 + t * 16 + g * 4 + r] = fmaf(alpha, attn, 1.0f);
            }
        }
    }
    __syncthreads();

    // ---- coalesced gate sweep: out = PRV * (1 + alpha*attn) ----
    const size_t base = (size_t)blockIdx.x * 256 * (C_DIM / 4);
    const float4* prv4 = reinterpret_cast<const float4*>(PRV) + base;
    float4* out4 = reinterpret_cast<float4*>(out) + base;
    #pragma unroll 4
    for (int it = 0; it < 16; ++it) {
        int idx = it * 512 + tid;
        float sc = s_scale[idx >> 5];   // 32 float4 per row
        float4 v = prv4[idx];
        v.x *= sc; v.y *= sc; v.z *= sc; v.w *= sc;
        out4[idx] = v;
    }
}

extern "C" void kernel_launch(void* const* d_in, const int* in_sizes, int n_in,
                              void* d_out, int out_size, void* d_ws, size_t ws_size,
                              hipStream_t stream) {
    const float* PRV    = (const float*)d_in[0];
    const float* PR     = (const float*)d_in[1];
    const float* c1     = (const float*)d_in[2];
    const float* gamma  = (const float*)d_in[3];
    const float* beta   = (const float*)d_in[4];
    const float* c2     = (const float*)d_in[5];
    const float* alphap = (const float*)d_in[6];
    float* out = (float*)d_out;

    unsigned short* Bpack = (unsigned short*)d_ws;            // 32 KB bf16 frags
    float* wsf   = (float*)((char*)d_ws + 32768);
    float* bias1 = wsf;          // 32
    float* E2    = wsf + 32;     // 128 (32 x float4)
    float* bias2 = wsf + 160;    // 1

    const int N = in_sizes[0] / C_DIM;

    hipLaunchKernelGGL(prep_kernel, dim3(64), dim3(256), 0, stream,
                       c1, c2, Bpack, bias1, E2, bias2);
    hipLaunchKernelGGL(fused_kernel, dim3(N / 256), dim3(512), 0, stream,
                       PRV, PR, Bpack, bias1, E2, bias2, gamma, beta, alphap, out);
}